// Round 12
// baseline (131.070 us; speedup 1.0000x reference)
//
#include <hip/hip_runtime.h>
#include <stdint.h>

// HierarchicalZ2_12Quantizer on MI355X (gfx950) — 1-wave-block 2-tile pipeline.
// tokens = 8*4096 = 32768, D = 1024
// R11 post-mortem: mixing idea starved at 4 waves/CU (98KB LDS). R12:
// 1-wave blocks (grid 1024, 64 thr), 32 tokens = tiles A+B, LDS 16.6KB ->
// 9 blocks/CU. Middle phase: epi(A) || down(B), depth-2 prefetch on all
// streams -> counted waits (vmcnt 24) never touch stores younger than ~2
// iterations. Down chunks 64 cols (4 DMA, tri-buffer), swizzle cb^((row&7)<<1).
// codes from bit patterns: c[j][i] = ((j>>(n-1-i))&1)?+1:-1.

#define DM 1024
#define OUT_OFF ((size_t)33554432)  // 8*4096*1024
#define NTOK 32768
#define NSLOT 32
#define WSA_OFF 32768               // float offset of gate-acc in ws

typedef float f32x4 __attribute__((ext_vector_type(4)));
typedef short bf16x8 __attribute__((ext_vector_type(8)));

typedef const __attribute__((address_space(1))) unsigned int* gas1_t;
typedef __attribute__((address_space(3))) unsigned int* las3_t;

__device__ __forceinline__ void gl_lds16(const void* g, void* l){
  __builtin_amdgcn_global_load_lds((gas1_t)g, (las3_t)l, 16, 0, 0);
}

__device__ __forceinline__ short f2bf(float f){
  unsigned u = __builtin_bit_cast(unsigned, f);
  unsigned r = u + 0x7fffu + ((u >> 16) & 1u);   // round-to-nearest-even
  return (short)(r >> 16);
}

// soft_quantize over the 2^NB hypercube corners; z[NB] -> q[NB]
template<int NB>
__device__ __forceinline__ void softq(const float* z, float invt, float* q){
  constexpr int K = 1 << NB;
  float d[K];
  float dmin = 3.4e38f;
#pragma unroll
  for (int j = 0; j < K; ++j){
    float acc = 0.f;
#pragma unroll
    for (int i = 0; i < NB; ++i){
      float c = ((j >> (NB-1-i)) & 1) ? 1.f : -1.f;
      float t = z[i] - c;
      acc = fmaf(t, t, acc);
    }
    float dj = sqrtf(acc);
    d[j] = dj;
    dmin = fminf(dmin, dj);
  }
  float S = 0.f;
  float s1[NB];
#pragma unroll
  for (int i = 0; i < NB; ++i) s1[i] = 0.f;
#pragma unroll
  for (int j = 0; j < K; ++j){
    float wj = __expf((dmin - d[j]) * invt);
    S += wj;
#pragma unroll
    for (int i = 0; i < NB; ++i)
      if ((j >> (NB-1-i)) & 1) s1[i] += wj;   // compile-time bit -> no branch
  }
  float rS = 1.f / S;
#pragma unroll
  for (int i = 0; i < NB; ++i) q[i] = 2.f * s1[i] * rS - 1.f;  // (S1-S0)/S
}

// ---------------- pack: weights -> bf16 B-fragments in ws (once) ------------
__global__ __launch_bounds__(256) void pack_kernel(
    const float* __restrict__ w_to_l1,  const float* __restrict__ w_to_l2,
    const float* __restrict__ w_to_l3u, const float* __restrict__ w_to_l3l,
    const float* __restrict__ w_gate,
    const float* __restrict__ w_from_l1, const float* __restrict__ w_from_l2,
    const float* __restrict__ w_from_l3,
    short* __restrict__ wsF, float* __restrict__ wsA)
{
  int base = blockIdx.x*4096 + threadIdx.x*16;
#pragma unroll
  for (int q = 0; q < 16; ++q){
    int e = base + q;
    float v;
    if (e < 32768){
      int s  = e >> 10;
      int nf = (e >> 9) & 1;
      int ll = (e >> 3) & 63;
      int j  = e & 7;
      int k  = s*32 + ((ll >> 4) << 3) + j;
      int n  = nf*16 + (ll & 15);
      if      (n < 3)  v = w_gate  [k*3 + n];
      else if (n < 6)  v = w_to_l1 [k*3 + (n-3)];
      else if (n < 12) v = w_to_l2 [k*6 + (n-6)];
      else if (n < 18) v = w_to_l3u[k*6 + (n-12)];
      else if (n < 24) v = w_to_l3l[k*6 + (n-18)];
      else             v = 0.f;
    } else {
      int e2  = e - 32768;
      int f   = e2 / 384;
      int rem = e2 - f*384;
      int ll  = rem >> 3;
      int j   = e2 & 7;
      int k   = ((ll >> 4) << 3) + j;      // 0..23
      int dd  = f*16 + (ll & 15);
      if      (k < 3)  v = w_from_l1[k*DM + dd];
      else if (k < 9)  v = w_from_l2[(k-3)*DM + dd];
      else if (k < 21) v = w_from_l3[(k-9)*DM + dd];
      else             v = 0.f;
    }
    wsF[e] = f2bf(v);
  }
  if (blockIdx.x == 0){
    wsA[threadIdx.x]       = 0.f;
    wsA[threadIdx.x + 256] = 0.f;
  }
}

// ---- quantize 16 tokens, wave-local, lane group = role (accumulates sg) ----
__device__ __forceinline__ void quant16(const float* Pw, short* Vw, int l,
    float invt1, float invt2, float invt3, float s1v, float s2v, float s3v,
    float bg0, float bg1, float bg2, float& sg0, float& sg1, float& sg2)
{
  const int t  = l & 15;
  const int gi = l >> 4;   // 0:l2  1:l3u  2:l3l  3:gate+l1
  const int base = (gi == 3) ? 0 : 6 + gi*6;
  float z[6];
#pragma unroll
  for (int i = 0; i < 6; ++i) z[i] = Pw[t*34 + base + i];
  float qv[6] = {0,0,0,0,0,0};
  float myscale = 0.f, g1s2v = 0.f, g2s3v = 0.f;
  if (gi == 3){
    float g0l = z[0] + bg0;
    float g1l = z[1] + bg1;
    float g2l = z[2] + bg2;
    float m  = fmaxf(g0l, fmaxf(g1l, g2l));
    float e0 = __expf(g0l - m), e1 = __expf(g1l - m), e2 = __expf(g2l - m);
    float rs = 1.f / (e0 + e1 + e2);
    float g0 = e0*rs, g1 = e1*rs, g2 = e2*rs;
    myscale = g0 * s1v;
    g1s2v   = g1 * s2v;
    g2s3v   = g2 * s3v;
    float z1[3] = {z[3], z[4], z[5]};
    softq<3>(z1, invt1, qv);
    float a0 = g0, a1 = g1, a2 = g2;
#pragma unroll
    for (int mm = 1; mm < 16; mm <<= 1){
      a0 += __shfl_xor(a0, mm, 64);
      a1 += __shfl_xor(a1, mm, 64);
      a2 += __shfl_xor(a2, mm, 64);
    }
    sg0 += a0; sg1 += a1; sg2 += a2;
  } else {
    float invt = (gi == 0) ? invt2 : invt3;
    softq<6>(z, invt, qv);
  }
  float gs1 = __shfl(g1s2v, 48 + t, 64);
  float gs2 = __shfl(g2s3v, 48 + t, 64);
  if (gi == 3){
#pragma unroll
    for (int i = 0; i < 3; ++i) Vw[t*40 + i] = f2bf(myscale * qv[i]);
    Vw[t*40 + 21] = 0; Vw[t*40 + 22] = 0; Vw[t*40 + 23] = 0;  // kg=2 tail
  } else {
    float sc = (gi == 0) ? gs1 : gs2;
    int voff = 3 + gi*6;
#pragma unroll
    for (int i = 0; i < 6; ++i) Vw[t*40 + voff + i] = f2bf(sc * qv[i]);
  }
}

struct EpiL { bf16x8 b0, b1, b2, b3; f32x4 x0, x1, x2, x3; };

__device__ __forceinline__ EpiL epi_load(int c, const short* wsFC,
                                         const float* xT, int l, int kg,
                                         int rl, int cs){
  EpiL L;
  bf16x8 z8 = {0,0,0,0,0,0,0,0};
  L.b0 = z8; L.b1 = z8; L.b2 = z8; L.b3 = z8;
  if (kg < 3){
    L.b0 = *reinterpret_cast<const bf16x8*>(&wsFC[(c*4+0)*384 + l*8]);
    L.b1 = *reinterpret_cast<const bf16x8*>(&wsFC[(c*4+1)*384 + l*8]);
    L.b2 = *reinterpret_cast<const bf16x8*>(&wsFC[(c*4+2)*384 + l*8]);
    L.b3 = *reinterpret_cast<const bf16x8*>(&wsFC[(c*4+3)*384 + l*8]);
  }
  const float* xr = xT + (size_t)rl*DM + c*64 + cs*4;
  L.x0 = *reinterpret_cast<const f32x4*>(xr);
  L.x1 = *reinterpret_cast<const f32x4*>(xr + 16);
  L.x2 = *reinterpret_cast<const f32x4*>(xr + 32);
  L.x3 = *reinterpret_cast<const f32x4*>(xr + 48);
  return L;
}

// DMA one 64-col chunk (16 rows x 256B = 4 ops), swizzled source
#define DMA64(xbase, k, bufptr)                                               \
  do {                                                                        \
    _Pragma("unroll")                                                         \
    for (int j_ = 0; j_ < 4; ++j_){                                           \
      int lr_ = j_*4 + (l >> 4);                                              \
      gl_lds16((xbase) + (size_t)lr_*DM + (k)*64 + ((l & 15) ^ ((lr_ & 7) << 1))*4, \
               (bufptr) + j_*1024 + l*16);                                    \
    }                                                                         \
  } while (0)

// consume one staged 64-col chunk: 2 k-steps x 2 nfrags MFMA
#define DOWN_CONSUME(bufptr, fb0_, fb1_, fb2_, fb3_, acc0_, acc1_)            \
  do {                                                                        \
    const char* ab_ = (bufptr) + ln16*256;                                    \
    { float4 xa_ = *reinterpret_cast<const float4*>(ab_ + ((kg*2+0) ^ ((ln16&7)<<1))*16); \
      float4 xb_ = *reinterpret_cast<const float4*>(ab_ + ((kg*2+1) ^ ((ln16&7)<<1))*16); \
      bf16x8 af_;                                                             \
      af_[0]=f2bf(xa_.x); af_[1]=f2bf(xa_.y); af_[2]=f2bf(xa_.z); af_[3]=f2bf(xa_.w); \
      af_[4]=f2bf(xb_.x); af_[5]=f2bf(xb_.y); af_[6]=f2bf(xb_.z); af_[7]=f2bf(xb_.w); \
      acc0_ = __builtin_amdgcn_mfma_f32_16x16x32_bf16(af_, fb0_, acc0_, 0, 0, 0); \
      acc1_ = __builtin_amdgcn_mfma_f32_16x16x32_bf16(af_, fb1_, acc1_, 0, 0, 0); } \
    { float4 xa_ = *reinterpret_cast<const float4*>(ab_ + ((8+kg*2+0) ^ ((ln16&7)<<1))*16); \
      float4 xb_ = *reinterpret_cast<const float4*>(ab_ + ((8+kg*2+1) ^ ((ln16&7)<<1))*16); \
      bf16x8 af_;                                                             \
      af_[0]=f2bf(xa_.x); af_[1]=f2bf(xa_.y); af_[2]=f2bf(xa_.z); af_[3]=f2bf(xa_.w); \
      af_[4]=f2bf(xb_.x); af_[5]=f2bf(xb_.y); af_[6]=f2bf(xb_.z); af_[7]=f2bf(xb_.w); \
      acc0_ = __builtin_amdgcn_mfma_f32_16x16x32_bf16(af_, fb2_, acc0_, 0, 0, 0); \
      acc1_ = __builtin_amdgcn_mfma_f32_16x16x32_bf16(af_, fb3_, acc1_, 0, 0, 0); } \
  } while (0)

// epi compute+store for chunk c (C transpose via LDS, coalesced f4 stores)
#define EPI_STORE(c_, Lb0_, Lb1_, Lb2_, Lb3_, xv0_, xv1_, xv2_, xv3_, aV_, outT_) \
  do {                                                                        \
    const f32x4 zz_ = {0.f,0.f,0.f,0.f};                                      \
    f32x4 d0_ = __builtin_amdgcn_mfma_f32_16x16x32_bf16(aV_, Lb0_, zz_, 0, 0, 0); \
    f32x4 d1_ = __builtin_amdgcn_mfma_f32_16x16x32_bf16(aV_, Lb1_, zz_, 0, 0, 0); \
    f32x4 d2_ = __builtin_amdgcn_mfma_f32_16x16x32_bf16(aV_, Lb2_, zz_, 0, 0, 0); \
    f32x4 d3_ = __builtin_amdgcn_mfma_f32_16x16x32_bf16(aV_, Lb3_, zz_, 0, 0, 0); \
    _Pragma("unroll")                                                         \
    for (int r_ = 0; r_ < 4; ++r_){                                           \
      int rb_ = (kg*4 + r_)*68;                                               \
      Cw[rb_ +  0 + ln16] = d0_[r_];                                          \
      Cw[rb_ + 16 + ln16] = d1_[r_];                                          \
      Cw[rb_ + 32 + ln16] = d2_[r_];                                          \
      Cw[rb_ + 48 + ln16] = d3_[r_];                                          \
    }                                                                         \
    __builtin_amdgcn_sched_barrier(0);                                        \
    asm volatile("s_waitcnt lgkmcnt(0)" ::: "memory");                        \
    __builtin_amdgcn_sched_barrier(0);                                        \
    f32x4 c0_ = *reinterpret_cast<const f32x4*>(&Cw[rl*68 + cs*4]);           \
    f32x4 c1_ = *reinterpret_cast<const f32x4*>(&Cw[rl*68 + cs*4 + 16]);      \
    f32x4 c2_ = *reinterpret_cast<const f32x4*>(&Cw[rl*68 + cs*4 + 32]);      \
    f32x4 c3_ = *reinterpret_cast<const f32x4*>(&Cw[rl*68 + cs*4 + 48]);      \
    float* or_ = (outT_) + (size_t)rl*DM + (c_)*64 + cs*4;                    \
    *reinterpret_cast<f32x4*>(or_)      = xv0_ + c0_;                         \
    *reinterpret_cast<f32x4*>(or_ + 16) = xv1_ + c1_;                         \
    *reinterpret_cast<f32x4*>(or_ + 32) = xv2_ + c2_;                         \
    *reinterpret_cast<f32x4*>(or_ + 48) = xv3_ + c3_;                         \
  } while (0)

// ---------------- fused 1-wave 2-tile pipeline ------------------------------
__global__ __launch_bounds__(64) void hq10_kernel(
    const float* __restrict__ x, const short* __restrict__ wsF,
    const float* __restrict__ b_gate,
    const float* __restrict__ t1p, const float* __restrict__ t2p, const float* __restrict__ t3p,
    const float* __restrict__ s1p, const float* __restrict__ s2p, const float* __restrict__ s3p,
    float* __restrict__ wsA, float* __restrict__ out)
{
  // LDS 16640B -> 9 blocks/CU:
  //  [0,12288)     staging: tri-buffer 3 x 4KB (64-col chunks)
  //  [0,2176)      P [16][34] f32 (overlay, only between phases)
  //  [2176,3456)   V [16][40] bf16 (overlay, only between phases)
  //  [12288,16640) C [16][68] f32
  __shared__ alignas(16) char smem[16640];
  float* Pw = reinterpret_cast<float*>(smem);
  short* Vw = reinterpret_cast<short*>(smem + 2176);
  float* Cw = reinterpret_cast<float*>(smem + 12288);

  const int l    = threadIdx.x;   // 0..63, one wave
  const int kg   = l >> 4;
  const int ln16 = l & 15;
  const int rl   = l >> 2;
  const int cs   = l & 3;

  const size_t tokA = (size_t)blockIdx.x * 32;
  const float* xA   = x + tokA*DM;
  const float* xB   = xA + (size_t)16*DM;
  float*       outA = out + tokA*DM;
  float*       outB = outA + (size_t)16*DM;
  const short* wsFC = wsF + 32768;
  const bf16x8 z8 = {0,0,0,0,0,0,0,0};

  // preload scalar params (s_load/lgkm — outside all vmcnt ledgers)
  const float invt1 = 1.f / fminf(fmaxf(__expf(t1p[0]), 0.01f), 5.0f);
  const float invt2 = 1.f / fminf(fmaxf(__expf(t2p[0]), 0.01f), 5.0f);
  const float invt3 = 1.f / fminf(fmaxf(__expf(t3p[0]), 0.01f), 5.0f);
  const float s1v = s1p[0], s2v = s2p[0], s3v = s3p[0];
  const float bg0 = b_gate[0], bg1 = b_gate[1], bg2 = b_gate[2];
  float sg0 = 0.f, sg1 = 0.f, sg2 = 0.f;

  // ============ phase 1: down(A), 16 x 64-col chunks, dbuf (bufs 0,1) =======
  f32x4 accA0 = {0.f,0.f,0.f,0.f}, accA1 = {0.f,0.f,0.f,0.f};
  DMA64(xA, 0, smem);
#pragma unroll
  for (int k = 0; k < 16; ++k){
    bf16x8 fb0 = *reinterpret_cast<const bf16x8*>(&wsF[(k*4+0)*512 + l*8]);
    bf16x8 fb1 = *reinterpret_cast<const bf16x8*>(&wsF[(k*4+1)*512 + l*8]);
    bf16x8 fb2 = *reinterpret_cast<const bf16x8*>(&wsF[(k*4+2)*512 + l*8]);
    bf16x8 fb3 = *reinterpret_cast<const bf16x8*>(&wsF[(k*4+3)*512 + l*8]);
    __builtin_amdgcn_sched_barrier(0);
    if (k < 15){
      DMA64(xA, k+1, smem + ((k+1)&1)*4096);
      asm volatile("s_waitcnt vmcnt(4)" ::: "memory");   // drains D(k)+fb(k)
    } else {
      asm volatile("s_waitcnt vmcnt(0)" ::: "memory");
    }
    __builtin_amdgcn_sched_barrier(0);
    DOWN_CONSUME(smem + (k&1)*4096, fb0, fb1, fb2, fb3, accA0, accA1);
  }

  // P(A) -> overlay (staging dead), quantize(A), aVA to regs
#pragma unroll
  for (int r = 0; r < 4; ++r){
    int row = kg*4 + r;
    Pw[row*34 + ln16]      = accA0[r];
    Pw[row*34 + 16 + ln16] = accA1[r];
  }
  quant16(Pw, Vw, l, invt1, invt2, invt3, s1v, s2v, s3v, bg0, bg1, bg2, sg0, sg1, sg2);
  bf16x8 aVA = z8;
  if (kg < 3) aVA = *reinterpret_cast<const bf16x8*>(&Vw[ln16*40 + kg*8]);
  asm volatile("s_waitcnt lgkmcnt(0)" ::: "memory");   // aVA safe before DMA clobbers buf0
  __builtin_amdgcn_sched_barrier(0);

  // ============ phase 2: epi(A) || down(B), depth-2 on all streams ==========
  EpiL LS[2];
  bf16x8 BS[2][4];
#pragma unroll
  for (int p = 0; p < 2; ++p){   // prologue sets 0,1: [bfrB, D_B, L] each
#pragma unroll
    for (int f = 0; f < 4; ++f)
      BS[p][f] = *reinterpret_cast<const bf16x8*>(&wsF[(p*4+f)*512 + l*8]);
    DMA64(xB, p, smem + p*4096);
    LS[p] = epi_load(p, wsFC, xA, l, kg, rl, cs);
    __builtin_amdgcn_sched_barrier(0);
  }

  f32x4 accB0 = {0.f,0.f,0.f,0.f}, accB1 = {0.f,0.f,0.f,0.f};
#pragma unroll
  for (int c = 0; c < 16; ++c){
    // waits derived from exact issue ledger (see R12 header comment)
    if (c == 0)       asm volatile("s_waitcnt vmcnt(16)" ::: "memory");
    else if (c == 1)  asm volatile("s_waitcnt vmcnt(20)" ::: "memory");
    else if (c == 15) asm volatile("s_waitcnt vmcnt(8)"  ::: "memory");
    else              asm volatile("s_waitcnt vmcnt(24)" ::: "memory");
    __builtin_amdgcn_sched_barrier(0);
    // down(B) chunk c consume (staged buf c%3 + BS[c&1])
    DOWN_CONSUME(smem + (c%3)*4096, BS[c&1][0], BS[c&1][1], BS[c&1][2], BS[c&1][3],
                 accB0, accB1);
    __builtin_amdgcn_sched_barrier(0);
    // capture epi regs, then issue next set: [bfrB(c+2), D_B(c+2), L(c+2)]
    bf16x8 eb0 = LS[c&1].b0, eb1 = LS[c&1].b1, eb2 = LS[c&1].b2, eb3 = LS[c&1].b3;
    f32x4  xv0 = LS[c&1].x0, xv1 = LS[c&1].x1, xv2 = LS[c&1].x2, xv3 = LS[c&1].x3;
    if (c < 14){
#pragma unroll
      for (int f = 0; f < 4; ++f)
        BS[c&1][f] = *reinterpret_cast<const bf16x8*>(&wsF[((c+2)*4+f)*512 + l*8]);
      DMA64(xB, c+2, smem + ((c+2)%3)*4096);
      LS[c&1] = epi_load(c+2, wsFC, xA, l, kg, rl, cs);
    }
    __builtin_amdgcn_sched_barrier(0);
    // epi(A) chunk c: MFMA -> C -> coalesced residual stores (newest vmem ops)
    EPI_STORE(c, eb0, eb1, eb2, eb3, xv0, xv1, xv2, xv3, aVA, outA);
    __builtin_amdgcn_sched_barrier(0);
  }

  // ============ phase 3: quantize(B) + epi(B) (depth-2 epi loads) ===========
#pragma unroll
  for (int r = 0; r < 4; ++r){
    int row = kg*4 + r;
    Pw[row*34 + ln16]      = accB0[r];
    Pw[row*34 + 16 + ln16] = accB1[r];
  }
  quant16(Pw, Vw, l, invt1, invt2, invt3, s1v, s2v, s3v, bg0, bg1, bg2, sg0, sg1, sg2);
  bf16x8 aVB = z8;
  if (kg < 3) aVB = *reinterpret_cast<const bf16x8*>(&Vw[ln16*40 + kg*8]);

  LS[0] = epi_load(0, wsFC, xB, l, kg, rl, cs);
  __builtin_amdgcn_sched_barrier(0);
  LS[1] = epi_load(1, wsFC, xB, l, kg, rl, cs);
  __builtin_amdgcn_sched_barrier(0);
#pragma unroll
  for (int c = 0; c < 16; ++c){
    if (c == 0)       asm volatile("s_waitcnt vmcnt(8)"  ::: "memory");
    else if (c == 1)  asm volatile("s_waitcnt vmcnt(12)" ::: "memory");
    else if (c == 15) asm volatile("s_waitcnt vmcnt(8)"  ::: "memory");
    else              asm volatile("s_waitcnt vmcnt(16)" ::: "memory");
    __builtin_amdgcn_sched_barrier(0);
    bf16x8 eb0 = LS[c&1].b0, eb1 = LS[c&1].b1, eb2 = LS[c&1].b2, eb3 = LS[c&1].b3;
    f32x4  xv0 = LS[c&1].x0, xv1 = LS[c&1].x1, xv2 = LS[c&1].x2, xv3 = LS[c&1].x3;
    if (c < 14)
      LS[c&1] = epi_load(c+2, wsFC, xB, l, kg, rl, cs);
    __builtin_amdgcn_sched_barrier(0);
    EPI_STORE(c, eb0, eb1, eb2, eb3, xv0, xv1, xv2, xv3, aVB, outB);
    __builtin_amdgcn_sched_barrier(0);
  }

  // gate sums -> spread ws slots (after all counted waits)
  if (l == 48){
    float* slot = wsA + (blockIdx.x & (NSLOT-1))*16;
    atomicAdd(slot + 0, sg0);
    atomicAdd(slot + 1, sg1);
    atomicAdd(slot + 2, sg2);
  }
}

// ---------------- finalize: reduce 32 gate slots -> out[OUT_OFF..+2] --------
__global__ void finalize_kernel(const float* __restrict__ wsA, float* __restrict__ out){
  if (threadIdx.x < 3){
    float s = 0.f;
    for (int j = 0; j < NSLOT; ++j) s += wsA[j*16 + threadIdx.x];
    out[OUT_OFF + threadIdx.x] = s * (1.f / (float)NTOK);
  }
}

extern "C" void kernel_launch(void* const* d_in, const int* in_sizes, int n_in,
                              void* d_out, int out_size, void* d_ws, size_t ws_size,
                              hipStream_t stream){
  (void)in_sizes; (void)n_in; (void)ws_size; (void)out_size;
  const float* x         = (const float*)d_in[0];
  // d_in[1] (codes_l1), d_in[2] (codes_l2) unused: corners derived from bits
  const float* w_to_l1   = (const float*)d_in[3];
  const float* w_from_l1 = (const float*)d_in[4];
  const float* w_to_l2   = (const float*)d_in[5];
  const float* w_from_l2 = (const float*)d_in[6];
  const float* w_to_l3u  = (const float*)d_in[7];
  const float* w_to_l3l  = (const float*)d_in[8];
  const float* w_from_l3 = (const float*)d_in[9];
  const float* w_gate    = (const float*)d_in[10];
  const float* b_gate    = (const float*)d_in[11];
  const float* t1 = (const float*)d_in[12];
  const float* t2 = (const float*)d_in[13];
  const float* t3 = (const float*)d_in[14];
  const float* s1 = (const float*)d_in[15];
  const float* s2 = (const float*)d_in[16];
  const float* s3 = (const float*)d_in[17];
  float* out  = (float*)d_out;
  short* wsF  = (short*)d_ws;                       // 57344 shorts of fragments
  float* wsA  = (float*)d_ws + WSA_OFF;             // 32 slots x 16 floats

  pack_kernel<<<dim3(14), dim3(256), 0, stream>>>(
      w_to_l1, w_to_l2, w_to_l3u, w_to_l3l, w_gate,
      w_from_l1, w_from_l2, w_from_l3, wsF, wsA);
  hq10_kernel<<<dim3(1024), dim3(64), 0, stream>>>(
      x, wsF, b_gate, t1, t2, t3, s1, s2, s3, wsA, out);
  finalize_kernel<<<dim3(1), dim3(64), 0, stream>>>(wsA, out);
}